// Round 6
// baseline (372.662 us; speedup 1.0000x reference)
//
#include <hip/hip_runtime.h>
#include <hip/hip_bf16.h>

#define N_NODES 100000
#define N_EDGES 1600000
#define D 128
#define SCAN_N (N_NODES + 1)   // 100001
#define SCAN_BLOCKS 98         // 98 * 1024 = 100352 >= SCAN_N
#define NGROUP 8               // hist privatization groups
#define NSLICE 8               // column slices (16 cols each), slice = blockIdx&7

typedef __attribute__((ext_vector_type(8))) short short8;
typedef __attribute__((ext_vector_type(4))) float f32x4;

__device__ inline unsigned short f2bf(float f) {
  union { float f; unsigned u; } c; c.f = f;
  const unsigned u = c.u;
  return (unsigned short)((u + 0x7FFF + ((u >> 16) & 1)) >> 16);  // RNE
}
__device__ inline float bflo(unsigned u) { return __int_as_float(u << 16); }
__device__ inline float bfhi(unsigned u) { return __int_as_float(u & 0xFFFF0000u); }

// ---------------------------------------------------------------------------
// GEMM (bf16 MFMA): support_s[slice][n][c] = (x@W + lin_bias)[n][slice*16+c]
// 128 rows/block, 256 threads (4 waves). Slice-major bf16 output: in the
// epilogue col = ct*16 + m16, so slice == ct.
// ---------------------------------------------------------------------------
#define GR 128
#define LDK 136
__global__ __launch_bounds__(256) void gemm_kernel(
    const float* __restrict__ x, const float* __restrict__ W,
    const float* __restrict__ lin_bias, unsigned short* __restrict__ support) {
  __shared__ unsigned short Wt[128 * LDK];  // W transposed: Wt[n][k]
  __shared__ unsigned short xb[GR * LDK];   // xb[r][k]
  const int t = threadIdx.x;
  const int row0 = blockIdx.x * GR;

  for (int i = t; i < 128 * 32; i += 256) {
    const int k = i >> 5, n4 = (i & 31) * 4;
    const float4 w = *(const float4*)(W + k * D + n4);
    Wt[(n4 + 0) * LDK + k] = f2bf(w.x);
    Wt[(n4 + 1) * LDK + k] = f2bf(w.y);
    Wt[(n4 + 2) * LDK + k] = f2bf(w.z);
    Wt[(n4 + 3) * LDK + k] = f2bf(w.w);
  }
  for (int i = t; i < GR * 32; i += 256) {
    const int r = i >> 5, k4 = (i & 31) * 4;
    const int row = row0 + r;
    float4 v = make_float4(0.f, 0.f, 0.f, 0.f);
    if (row < N_NODES) v = *(const float4*)(x + (size_t)row * D + k4);
    unsigned short* p = &xb[r * LDK + k4];
    p[0] = f2bf(v.x); p[1] = f2bf(v.y); p[2] = f2bf(v.z); p[3] = f2bf(v.w);
  }
  __syncthreads();

  const int w = t >> 6;
  const int lane = t & 63;
  const int m16 = lane & 15;
  const int quad = lane >> 4;

  f32x4 acc[2][8];
#pragma unroll
  for (int rt = 0; rt < 2; ++rt)
#pragma unroll
    for (int ct = 0; ct < 8; ++ct) acc[rt][ct] = (f32x4){0.f, 0.f, 0.f, 0.f};

#pragma unroll
  for (int kc = 0; kc < 4; ++kc) {
    const int kof = kc * 32 + quad * 8;
    short8 a0 = *(const short8*)&xb[(w * 32 + 0 * 16 + m16) * LDK + kof];
    short8 a1 = *(const short8*)&xb[(w * 32 + 1 * 16 + m16) * LDK + kof];
#pragma unroll
    for (int ct = 0; ct < 8; ++ct) {
      const short8 b = *(const short8*)&Wt[(ct * 16 + m16) * LDK + kof];
      acc[0][ct] = __builtin_amdgcn_mfma_f32_16x16x32_bf16(a0, b, acc[0][ct], 0, 0, 0);
      acc[1][ct] = __builtin_amdgcn_mfma_f32_16x16x32_bf16(a1, b, acc[1][ct], 0, 0, 0);
    }
  }

  // Epilogue: C/D layout col=lane&15, row=quad*4+reg. slice==ct. bf16 stores.
#pragma unroll
  for (int ct = 0; ct < 8; ++ct) {
    const float lb = lin_bias[ct * 16 + m16];
#pragma unroll
    for (int rt = 0; rt < 2; ++rt) {
      const int rbase = row0 + w * 32 + rt * 16 + quad * 4;
#pragma unroll
      for (int i = 0; i < 4; ++i) {
        const int row = rbase + i;
        if (row < N_NODES)
          support[((size_t)ct * N_NODES + row) * 16 + m16] =
              f2bf(acc[rt][ct][i] + lb);
      }
    }
  }
}

// ---------------------------------------------------------------------------
// CSR build: zero -> hist(rank) -> scan1 -> scan3(fused offsets+gofs) -> build
// ---------------------------------------------------------------------------
__global__ __launch_bounds__(256) void zero_kernel(int* __restrict__ p, int n) {
  const int i = blockIdx.x * 256 + threadIdx.x;
  if (i < n) p[i] = 0;
}

__global__ __launch_bounds__(256) void hist_kernel(
    const int* __restrict__ rows, int* __restrict__ count,
    unsigned char* __restrict__ rank) {
  const int e = blockIdx.x * 256 + threadIdx.x;   // grid == N_EDGES exactly
  const int g = blockIdx.x & (NGROUP - 1);
  const int r = rows[e];
  const int rg = atomicAdd(&count[r * NGROUP + g], 1);
  rank[e] = (unsigned char)rg;
}

// Per-block inclusive scan of degrees (deg[i] = degree of node i-1, deg[0]=0).
__global__ __launch_bounds__(1024) void scan1_kernel(
    const int* __restrict__ count, int* __restrict__ row_start,
    int* __restrict__ partials) {
  __shared__ int s[1024];
  const int t = threadIdx.x;
  const int i = blockIdx.x * 1024 + t;
  int deg = 0;
  if (i >= 1 && i <= N_NODES) {
    const int4* c4 = (const int4*)(count + (size_t)(i - 1) * NGROUP);
    const int4 a = c4[0], b = c4[1];
    deg = a.x + a.y + a.z + a.w + b.x + b.y + b.z + b.w;
  }
  s[t] = deg;
  __syncthreads();
#pragma unroll
  for (int d = 1; d < 1024; d <<= 1) {
    const int v = (t >= d) ? s[t - d] : 0;
    __syncthreads();
    s[t] += v;
    __syncthreads();
  }
  if (i < SCAN_N) row_start[i] = s[t];
  if (t == 1023) partials[blockIdx.x] = s[1023];
}

// Finalize row_start (block offset computed in-kernel from partials) and
// convert count[r*8+g] in place into per-(row,group) offsets.
__global__ __launch_bounds__(1024) void scan3_kernel(
    int* __restrict__ row_start, const int* __restrict__ partials,
    int* __restrict__ count) {
  __shared__ int sp[128];
  const int t = threadIdx.x;
  if (t < 128) sp[t] = (t < (int)blockIdx.x) ? partials[t] : 0;
  __syncthreads();
#pragma unroll
  for (int w = 64; w >= 1; w >>= 1) {
    if (t < w) sp[t] += sp[t + w];
    __syncthreads();
  }
  const int add = sp[0];
  const int i = blockIdx.x * 1024 + t;
  if (i < SCAN_N) {
    const int v = row_start[i] + add;
    row_start[i] = v;
    if (i < N_NODES) {
      int* c = count + (size_t)i * NGROUP;
      int base = v;
#pragma unroll
      for (int g = 0; g < NGROUP; ++g) {
        const int tmp = c[g];
        c[g] = base;
        base += tmp;
      }
    }
  }
}

// No atomics: pos = gofs[r][g] + rank[e]. Packed pair: (col<<15) | q15(val).
__global__ __launch_bounds__(256) void build_kernel(
    const int* __restrict__ rows, const int* __restrict__ cols,
    const float* __restrict__ vals, const int* __restrict__ gofs,
    const unsigned char* __restrict__ rank, unsigned* __restrict__ pairs) {
  const int e = blockIdx.x * 256 + threadIdx.x;   // grid == N_EDGES exactly
  const int g = blockIdx.x & (NGROUP - 1);
  const int r = rows[e];
  const int pos = gofs[(size_t)r * NGROUP + g] + (int)rank[e];
  const unsigned q = (unsigned)(vals[e] * 32767.f + 0.5f);
  pairs[pos] = ((unsigned)cols[e] << 15) | q;
}

// ---------------------------------------------------------------------------
// Gather, XCD-sliced: slice = blockIdx&7 (round-robin block->XCD keeps each
// XCD's support working set at 3.2 MB < 4 MiB L2). 4 lanes per row, 64 rows
// per block; lane d covers 4 cols via one uint2 (4 bf16) per edge.
// ---------------------------------------------------------------------------
__global__ __launch_bounds__(256) void gather_kernel(
    const int* __restrict__ row_start, const unsigned* __restrict__ pairs,
    const uint2* __restrict__ support, const float* __restrict__ bias,
    float* __restrict__ out) {
  const int slice = blockIdx.x & (NSLICE - 1);
  const int rowblk = blockIdx.x >> 3;
  const int t = threadIdx.x;
  const int r = rowblk * 64 + (t >> 2);
  const int d = t & 3;
  if (r >= N_NODES) return;
  const int e0 = row_start[r];
  const int e1 = row_start[r + 1];
  const uint2* sup = support + (size_t)slice * N_NODES * 4;

  float4 acc0 = make_float4(0.f, 0.f, 0.f, 0.f);
  float4 acc1 = make_float4(0.f, 0.f, 0.f, 0.f);
  int e = e0;
  for (; e + 1 < e1; e += 2) {
    const unsigned pa = pairs[e];
    const unsigned pb = pairs[e + 1];
    const uint2 sa = sup[(size_t)(pa >> 15) * 4 + d];
    const uint2 sb = sup[(size_t)(pb >> 15) * 4 + d];
    const float va = (float)(pa & 0x7FFFu) * (1.f / 32767.f);
    const float vb = (float)(pb & 0x7FFFu) * (1.f / 32767.f);
    acc0.x += va * bflo(sa.x); acc0.y += va * bfhi(sa.x);
    acc0.z += va * bflo(sa.y); acc0.w += va * bfhi(sa.y);
    acc1.x += vb * bflo(sb.x); acc1.y += vb * bfhi(sb.x);
    acc1.z += vb * bflo(sb.y); acc1.w += vb * bfhi(sb.y);
  }
  if (e < e1) {
    const unsigned pa = pairs[e];
    const uint2 sa = sup[(size_t)(pa >> 15) * 4 + d];
    const float va = (float)(pa & 0x7FFFu) * (1.f / 32767.f);
    acc0.x += va * bflo(sa.x); acc0.y += va * bfhi(sa.x);
    acc0.z += va * bflo(sa.y); acc0.w += va * bfhi(sa.y);
  }
  const float4 b = ((const float4*)bias)[slice * 4 + d];
  float4 o;
  o.x = acc0.x + acc1.x + b.x;
  o.y = acc0.y + acc1.y + b.y;
  o.z = acc0.z + acc1.z + b.z;
  o.w = acc0.w + acc1.w + b.w;
  *(float4*)(out + (size_t)r * D + slice * 16 + d * 4) = o;
}

// ---------------------------------------------------------------------------
// Fallback (atomic path, slice-major bf16 support) if workspace too small.
// ---------------------------------------------------------------------------
__global__ __launch_bounds__(256) void init_out_kernel(
    const float* __restrict__ bias, float* __restrict__ out) {
  const size_t idx = (size_t)blockIdx.x * 256 + threadIdx.x;
  const float4 b = ((const float4*)bias)[idx & 31];
  ((float4*)out)[idx] = b;
}

__global__ __launch_bounds__(256) void scatter_kernel(
    const int* __restrict__ rows, const int* __restrict__ cols,
    const float* __restrict__ vals, const uint2* __restrict__ support,
    float* __restrict__ out) {
  const size_t tid = (size_t)blockIdx.x * 256 + threadIdx.x;
  const int e = (int)(tid >> 5);
  const int q = (int)(tid & 31);
  const int r = rows[e];
  const int c = cols[e];
  const float v = vals[e];
  const uint2 s = support[((size_t)(q >> 2) * N_NODES + c) * 4 + (q & 3)];
  float* o = out + (size_t)r * D + 4 * q;
  atomicAdd(o + 0, v * bflo(s.x));
  atomicAdd(o + 1, v * bfhi(s.x));
  atomicAdd(o + 2, v * bflo(s.y));
  atomicAdd(o + 3, v * bfhi(s.y));
}

extern "C" void kernel_launch(void* const* d_in, const int* in_sizes, int n_in,
                              void* d_out, int out_size, void* d_ws, size_t ws_size,
                              hipStream_t stream) {
  const float* x        = (const float*)d_in[0];
  const float* W        = (const float*)d_in[1];
  const float* lin_bias = (const float*)d_in[2];
  const float* bias     = (const float*)d_in[3];
  const int*   adj_rows = (const int*)d_in[4];
  const int*   adj_cols = (const int*)d_in[5];
  const float* adj_vals = (const float*)d_in[6];
  float* out = (float*)d_out;

  // Workspace layout (16B-aligned offsets):
  //   support   : 25,600,000 B  (NSLICE x N_NODES x 16 bf16, slice-major)
  //   row_start :    400,016 B  (SCAN_N ints, padded)
  //   count/gofs:  3,200,000 B  (N_NODES*8 ints)
  //   rank      :  1,600,000 B  (N_EDGES u8)
  //   pairs     :  6,400,000 B  (N_EDGES u32, packed col|q15)
  //   partials  :        512 B
  char* wsb = (char*)d_ws;
  unsigned short* support   = (unsigned short*)wsb;
  int*            row_start = (int*)(wsb + 25600000);
  int*            count     = (int*)(wsb + 26000016);
  unsigned char*  rank      = (unsigned char*)(wsb + 29200016);
  unsigned*       pairs     = (unsigned*)(wsb + 30800016);
  int*            partials  = (int*)(wsb + 37200016);
  const size_t ws_needed = 37200528;

  gemm_kernel<<<(N_NODES + GR - 1) / GR, 256, 0, stream>>>(x, W, lin_bias,
                                                           support);

  if (ws_size >= ws_needed) {
    zero_kernel<<<(N_NODES * NGROUP) / 256, 256, 0, stream>>>(count,
                                                              N_NODES * NGROUP);
    hist_kernel<<<N_EDGES / 256, 256, 0, stream>>>(adj_rows, count, rank);
    scan1_kernel<<<SCAN_BLOCKS, 1024, 0, stream>>>(count, row_start, partials);
    scan3_kernel<<<SCAN_BLOCKS, 1024, 0, stream>>>(row_start, partials, count);
    build_kernel<<<N_EDGES / 256, 256, 0, stream>>>(adj_rows, adj_cols,
                                                    adj_vals, count, rank,
                                                    pairs);
    const int rowblks = (N_NODES + 63) / 64;   // 1563
    gather_kernel<<<rowblks * NSLICE, 256, 0, stream>>>(
        row_start, pairs, (const uint2*)support, bias, out);
  } else {
    init_out_kernel<<<12500, 256, 0, stream>>>(bias, out);
    scatter_kernel<<<200000, 256, 0, stream>>>(adj_rows, adj_cols, adj_vals,
                                               (const uint2*)support, out);
  }
}

// Round 7
// 332.091 us; speedup vs baseline: 1.1222x; 1.1222x over previous
//
#include <hip/hip_runtime.h>
#include <hip/hip_bf16.h>

#define N_NODES 100000
#define N_EDGES 1600000
#define D 128
#define SCAN_N (N_NODES + 1)   // 100001
#define SCAN_BLOCKS 98         // 98 * 1024 = 100352 >= SCAN_N
#define NGROUP 8               // hist privatization groups

typedef __attribute__((ext_vector_type(8))) short short8;
typedef __attribute__((ext_vector_type(4))) float f32x4;

__device__ inline unsigned short f2bf(float f) {
  union { float f; unsigned u; } c; c.f = f;
  const unsigned u = c.u;
  return (unsigned short)((u + 0x7FFF + ((u >> 16) & 1)) >> 16);  // RNE
}
__device__ inline float bflo(unsigned u) { return __int_as_float(u << 16); }
__device__ inline float bfhi(unsigned u) { return __int_as_float(u & 0xFFFF0000u); }

// ---------------------------------------------------------------------------
// GEMM (bf16 MFMA): support[n][j] = bf16((x@W + lin_bias)[n][j]), row-major.
// 128 rows/block, 256 threads (4 waves). Also zeroes count[] (saves a launch).
// ---------------------------------------------------------------------------
#define GR 128
#define LDK 136
__global__ __launch_bounds__(256) void gemm_kernel(
    const float* __restrict__ x, const float* __restrict__ W,
    const float* __restrict__ lin_bias, unsigned short* __restrict__ support,
    int* __restrict__ count) {
  __shared__ unsigned short Wt[128 * LDK];  // W transposed: Wt[n][k]
  __shared__ unsigned short xb[GR * LDK];   // xb[r][k]
  const int t = threadIdx.x;
  const int row0 = blockIdx.x * GR;

  // Fold in zeroing of count[N_NODES*NGROUP] (800000 ints, 200000 int4s).
  if (count) {
    const int zi = (blockIdx.x * 256 + t) * 4;
    if (zi < N_NODES * NGROUP) *(int4*)(count + zi) = make_int4(0, 0, 0, 0);
  }

  for (int i = t; i < 128 * 32; i += 256) {
    const int k = i >> 5, n4 = (i & 31) * 4;
    const float4 w = *(const float4*)(W + k * D + n4);
    Wt[(n4 + 0) * LDK + k] = f2bf(w.x);
    Wt[(n4 + 1) * LDK + k] = f2bf(w.y);
    Wt[(n4 + 2) * LDK + k] = f2bf(w.z);
    Wt[(n4 + 3) * LDK + k] = f2bf(w.w);
  }
  for (int i = t; i < GR * 32; i += 256) {
    const int r = i >> 5, k4 = (i & 31) * 4;
    const int row = row0 + r;
    float4 v = make_float4(0.f, 0.f, 0.f, 0.f);
    if (row < N_NODES) v = *(const float4*)(x + (size_t)row * D + k4);
    unsigned short* p = &xb[r * LDK + k4];
    p[0] = f2bf(v.x); p[1] = f2bf(v.y); p[2] = f2bf(v.z); p[3] = f2bf(v.w);
  }
  __syncthreads();

  const int w = t >> 6;
  const int lane = t & 63;
  const int m16 = lane & 15;
  const int quad = lane >> 4;

  f32x4 acc[2][8];
#pragma unroll
  for (int rt = 0; rt < 2; ++rt)
#pragma unroll
    for (int ct = 0; ct < 8; ++ct) acc[rt][ct] = (f32x4){0.f, 0.f, 0.f, 0.f};

#pragma unroll
  for (int kc = 0; kc < 4; ++kc) {
    const int kof = kc * 32 + quad * 8;
    short8 a0 = *(const short8*)&xb[(w * 32 + 0 * 16 + m16) * LDK + kof];
    short8 a1 = *(const short8*)&xb[(w * 32 + 1 * 16 + m16) * LDK + kof];
#pragma unroll
    for (int ct = 0; ct < 8; ++ct) {
      const short8 b = *(const short8*)&Wt[(ct * 16 + m16) * LDK + kof];
      acc[0][ct] = __builtin_amdgcn_mfma_f32_16x16x32_bf16(a0, b, acc[0][ct], 0, 0, 0);
      acc[1][ct] = __builtin_amdgcn_mfma_f32_16x16x32_bf16(a1, b, acc[1][ct], 0, 0, 0);
    }
  }

  // Epilogue: C/D layout col=lane&15, row=quad*4+reg. Row-major bf16 stores.
#pragma unroll
  for (int ct = 0; ct < 8; ++ct) {
    const int col = ct * 16 + m16;
    const float lb = lin_bias[col];
#pragma unroll
    for (int rt = 0; rt < 2; ++rt) {
      const int rbase = row0 + w * 32 + rt * 16 + quad * 4;
#pragma unroll
      for (int i = 0; i < 4; ++i) {
        const int row = rbase + i;
        if (row < N_NODES)
          support[(size_t)row * D + col] = f2bf(acc[rt][ct][i] + lb);
      }
    }
  }
}

// ---------------------------------------------------------------------------
// CSR build: hist(rank) -> scan1 -> scan3(fused offsets+gofs) -> build
// ---------------------------------------------------------------------------
__global__ __launch_bounds__(256) void hist_kernel(
    const int* __restrict__ rows, int* __restrict__ count,
    unsigned char* __restrict__ rank) {
  const int e = blockIdx.x * 256 + threadIdx.x;   // grid == N_EDGES exactly
  const int g = blockIdx.x & (NGROUP - 1);
  const int r = rows[e];
  const int rg = atomicAdd(&count[r * NGROUP + g], 1);
  rank[e] = (unsigned char)rg;
}

// Per-block inclusive scan of degrees (deg[i] = degree of node i-1, deg[0]=0).
__global__ __launch_bounds__(1024) void scan1_kernel(
    const int* __restrict__ count, int* __restrict__ row_start,
    int* __restrict__ partials) {
  __shared__ int s[1024];
  const int t = threadIdx.x;
  const int i = blockIdx.x * 1024 + t;
  int deg = 0;
  if (i >= 1 && i <= N_NODES) {
    const int4* c4 = (const int4*)(count + (size_t)(i - 1) * NGROUP);
    const int4 a = c4[0], b = c4[1];
    deg = a.x + a.y + a.z + a.w + b.x + b.y + b.z + b.w;
  }
  s[t] = deg;
  __syncthreads();
#pragma unroll
  for (int d = 1; d < 1024; d <<= 1) {
    const int v = (t >= d) ? s[t - d] : 0;
    __syncthreads();
    s[t] += v;
    __syncthreads();
  }
  if (i < SCAN_N) row_start[i] = s[t];
  if (t == 1023) partials[blockIdx.x] = s[1023];
}

// Finalize row_start (block offset from partials, computed in-kernel) and
// convert count[r*8+g] in place into per-(row,group) offsets.
__global__ __launch_bounds__(1024) void scan3_kernel(
    int* __restrict__ row_start, const int* __restrict__ partials,
    int* __restrict__ count) {
  __shared__ int sp[128];
  const int t = threadIdx.x;
  if (t < 128) sp[t] = (t < (int)blockIdx.x) ? partials[t] : 0;
  __syncthreads();
#pragma unroll
  for (int w = 64; w >= 1; w >>= 1) {
    if (t < w) sp[t] += sp[t + w];
    __syncthreads();
  }
  const int add = sp[0];
  const int i = blockIdx.x * 1024 + t;
  if (i < SCAN_N) {
    const int v = row_start[i] + add;
    row_start[i] = v;
    if (i < N_NODES) {
      int* c = count + (size_t)i * NGROUP;
      int base = v;
#pragma unroll
      for (int g = 0; g < NGROUP; ++g) {
        const int tmp = c[g];
        c[g] = base;
        base += tmp;
      }
    }
  }
}

// No atomics: pos = gofs[r][g] + rank[e]. Packed pair: (col<<15) | q15(val).
__global__ __launch_bounds__(256) void build_kernel(
    const int* __restrict__ rows, const int* __restrict__ cols,
    const float* __restrict__ vals, const int* __restrict__ gofs,
    const unsigned char* __restrict__ rank, unsigned* __restrict__ pairs) {
  const int e = blockIdx.x * 256 + threadIdx.x;   // grid == N_EDGES exactly
  const int g = blockIdx.x & (NGROUP - 1);
  const int r = rows[e];
  const int pos = gofs[(size_t)r * NGROUP + g] + (int)rank[e];
  const unsigned q = (unsigned)(vals[e] * 32767.f + 0.5f);
  pairs[pos] = ((unsigned)cols[e] << 15) | q;
}

// ---------------------------------------------------------------------------
// Gather: one wave per row. 4 edges processed in parallel (lane groups of 16);
// each group loads its edge's support row as 16 x uint4 = 256 B coalesced,
// so one wave load instruction moves 1 KB. Unroll x2 -> 2 KB in flight/wave.
// Final shfl_xor(16,32) folds the 4 edge slots; lanes 0-15 write the row.
// ---------------------------------------------------------------------------
__global__ __launch_bounds__(256) void gather_kernel(
    const int* __restrict__ row_start, const unsigned* __restrict__ pairs,
    const uint4* __restrict__ support, const float* __restrict__ bias,
    float* __restrict__ out) {
  const int r = blockIdx.x * 4 + (threadIdx.x >> 6);
  if (r >= N_NODES) return;
  const int lane = threadIdx.x & 63;
  const int g = lane >> 4;        // edge slot 0..3
  const int c16 = lane & 15;      // 16B chunk (8 bf16 cols): cols c16*8..+7
  const int e0 = row_start[r];
  const int e1 = row_start[r + 1];

  float acc[8];
#pragma unroll
  for (int i = 0; i < 8; ++i) acc[i] = 0.f;

  for (int e = e0; e < e1; e += 8) {
    const int ea = e + g;
    const int eb = e + 4 + g;
    const unsigned pa = pairs[min(ea, e1 - 1)];
    const unsigned pb = pairs[min(eb, e1 - 1)];
    const float va = (ea < e1) ? (float)(pa & 0x7FFFu) * (1.f / 32767.f) : 0.f;
    const float vb = (eb < e1) ? (float)(pb & 0x7FFFu) * (1.f / 32767.f) : 0.f;
    const uint4 sa = support[(size_t)(pa >> 15) * 16 + c16];
    const uint4 sb = support[(size_t)(pb >> 15) * 16 + c16];
    acc[0] += va * bflo(sa.x); acc[1] += va * bfhi(sa.x);
    acc[2] += va * bflo(sa.y); acc[3] += va * bfhi(sa.y);
    acc[4] += va * bflo(sa.z); acc[5] += va * bfhi(sa.z);
    acc[6] += va * bflo(sa.w); acc[7] += va * bfhi(sa.w);
    acc[0] += vb * bflo(sb.x); acc[1] += vb * bfhi(sb.x);
    acc[2] += vb * bflo(sb.y); acc[3] += vb * bfhi(sb.y);
    acc[4] += vb * bflo(sb.z); acc[5] += vb * bfhi(sb.z);
    acc[6] += vb * bflo(sb.w); acc[7] += vb * bfhi(sb.w);
  }

  // Fold the 4 edge slots (lanes l, l^16, l^32, l^48 hold the same cols).
#pragma unroll
  for (int i = 0; i < 8; ++i) {
    acc[i] += __shfl_xor(acc[i], 16, 64);
    acc[i] += __shfl_xor(acc[i], 32, 64);
  }

  if (g == 0) {
    const float4 b0 = ((const float4*)bias)[c16 * 2 + 0];
    const float4 b1 = ((const float4*)bias)[c16 * 2 + 1];
    float4 o0, o1;
    o0.x = acc[0] + b0.x; o0.y = acc[1] + b0.y;
    o0.z = acc[2] + b0.z; o0.w = acc[3] + b0.w;
    o1.x = acc[4] + b1.x; o1.y = acc[5] + b1.y;
    o1.z = acc[6] + b1.z; o1.w = acc[7] + b1.w;
    float* op = out + (size_t)r * D + c16 * 8;
    *(float4*)(op + 0) = o0;
    *(float4*)(op + 4) = o1;
  }
}

// ---------------------------------------------------------------------------
// Fallback (atomic path, row-major bf16 support) if workspace too small.
// ---------------------------------------------------------------------------
__global__ __launch_bounds__(256) void init_out_kernel(
    const float* __restrict__ bias, float* __restrict__ out) {
  const size_t idx = (size_t)blockIdx.x * 256 + threadIdx.x;
  const float4 b = ((const float4*)bias)[idx & 31];
  ((float4*)out)[idx] = b;
}

__global__ __launch_bounds__(256) void scatter_kernel(
    const int* __restrict__ rows, const int* __restrict__ cols,
    const float* __restrict__ vals, const uint2* __restrict__ support,
    float* __restrict__ out) {
  const size_t tid = (size_t)blockIdx.x * 256 + threadIdx.x;
  const int e = (int)(tid >> 5);
  const int q = (int)(tid & 31);
  const int r = rows[e];
  const int c = cols[e];
  const float v = vals[e];
  const uint2 s = support[(size_t)c * 32 + q];
  float* o = out + (size_t)r * D + 4 * q;
  atomicAdd(o + 0, v * bflo(s.x));
  atomicAdd(o + 1, v * bfhi(s.x));
  atomicAdd(o + 2, v * bflo(s.y));
  atomicAdd(o + 3, v * bfhi(s.y));
}

extern "C" void kernel_launch(void* const* d_in, const int* in_sizes, int n_in,
                              void* d_out, int out_size, void* d_ws, size_t ws_size,
                              hipStream_t stream) {
  const float* x        = (const float*)d_in[0];
  const float* W        = (const float*)d_in[1];
  const float* lin_bias = (const float*)d_in[2];
  const float* bias     = (const float*)d_in[3];
  const int*   adj_rows = (const int*)d_in[4];
  const int*   adj_cols = (const int*)d_in[5];
  const float* adj_vals = (const float*)d_in[6];
  float* out = (float*)d_out;

  // Workspace layout (16B-aligned offsets):
  //   support   : 25,600,000 B  (N_NODES*D bf16, row-major)
  //   row_start :    400,016 B  (SCAN_N ints, padded)
  //   count/gofs:  3,200,000 B  (N_NODES*8 ints)
  //   rank      :  1,600,000 B  (N_EDGES u8)
  //   pairs     :  6,400,000 B  (N_EDGES u32, packed col|q15)
  //   partials  :        512 B
  char* wsb = (char*)d_ws;
  unsigned short* support   = (unsigned short*)wsb;
  int*            row_start = (int*)(wsb + 25600000);
  int*            count     = (int*)(wsb + 26000016);
  unsigned char*  rank      = (unsigned char*)(wsb + 29200016);
  unsigned*       pairs     = (unsigned*)(wsb + 30800016);
  int*            partials  = (int*)(wsb + 37200016);
  const size_t ws_needed = 37200528;

  const bool csr_path = (ws_size >= ws_needed);

  gemm_kernel<<<(N_NODES + GR - 1) / GR, 256, 0, stream>>>(
      x, W, lin_bias, support, csr_path ? count : nullptr);

  if (csr_path) {
    hist_kernel<<<N_EDGES / 256, 256, 0, stream>>>(adj_rows, count, rank);
    scan1_kernel<<<SCAN_BLOCKS, 1024, 0, stream>>>(count, row_start, partials);
    scan3_kernel<<<SCAN_BLOCKS, 1024, 0, stream>>>(row_start, partials, count);
    build_kernel<<<N_EDGES / 256, 256, 0, stream>>>(adj_rows, adj_cols,
                                                    adj_vals, count, rank,
                                                    pairs);
    gather_kernel<<<(N_NODES + 3) / 4, 256, 0, stream>>>(
        row_start, pairs, (const uint4*)support, bias, out);
  } else {
    init_out_kernel<<<12500, 256, 0, stream>>>(bias, out);
    scatter_kernel<<<200000, 256, 0, stream>>>(adj_rows, adj_cols, adj_vals,
                                               (const uint2*)support, out);
  }
}